// Round 1
// baseline (1184.747 us; speedup 1.0000x reference)
//
#include <hip/hip_runtime.h>
#include <hip/hip_bf16.h>

typedef __attribute__((ext_vector_type(8))) __bf16 bf16x8;
typedef __attribute__((ext_vector_type(4))) float f32x4;

#define MFMA(a,b,c) __builtin_amdgcn_mfma_f32_16x16x32_bf16((a),(b),(c),0,0,0)

__device__ __forceinline__ bf16x8 cvt8(float4 a, float4 b){
  bf16x8 r;
  r[0]=(__bf16)a.x; r[1]=(__bf16)a.y; r[2]=(__bf16)a.z; r[3]=(__bf16)a.w;
  r[4]=(__bf16)b.x; r[5]=(__bf16)b.y; r[6]=(__bf16)b.z; r[7]=(__bf16)b.w;
  return r;
}

// Pack 5 weight matrices [64][64] f32 (row = k/in-feature, col = n/out-feature)
// into bf16 MFMA B-fragments: frag (m, kt, nt), lane l holds 8 bf16
// B[k = kt*32 + (l>>4)*8 + j][n = nt*16 + (l&15)], stored so each lane's frag
// is one contiguous 16B load at Wp[(m*8 + kt*4 + nt)*64 + lane].
__global__ void wcvt(const float* __restrict__ W0, const float* __restrict__ W1,
                     const float* __restrict__ W2, const float* __restrict__ W3,
                     const float* __restrict__ W4, bf16x8* __restrict__ Wp){
  int tid = blockIdx.x*256 + threadIdx.x;
  if (tid >= 5*8*64) return;
  int lane = tid & 63, frag = (tid>>6)&7, m = tid>>9;
  const float* Ws[5] = {W0,W1,W2,W3,W4};
  const float* W = Ws[m];
  int kt = frag>>2, nt = frag&3, g = lane>>4, c = lane&15;
  bf16x8 v;
  #pragma unroll
  for (int j=0;j<8;j++){
    int k = kt*32 + g*8 + j, n = nt*16 + c;
    v[j] = (__bf16)W[k*64+n];
  }
  Wp[tid] = v;
}

// 4 node transforms in one pass: e_src, e_dst, A_src, Bh
__global__ __launch_bounds__(256) void node_xform(
    const float* __restrict__ nf, const bf16x8* __restrict__ Wp,
    const float* __restrict__ b_sg, const float* __restrict__ b_dg,
    const float* __restrict__ b_su, const float* __restrict__ b_du,
    float* __restrict__ e_src, float* __restrict__ e_dst,
    float* __restrict__ A_src, float* __restrict__ Bh, int ntiles)
{
  int lane = threadIdx.x & 63;
  int gw = blockIdx.x*4 + (threadIdx.x>>6);
  if (gw >= ntiles) return;
  int g = lane>>4, c = lane&15;
  long base = (long)gw*16;
  const float* rp = nf + (base + c)*64 + g*8;
  float4 a0 = *(const float4*)rp,      a1 = *(const float4*)(rp+4);
  float4 a2 = *(const float4*)(rp+32), a3 = *(const float4*)(rp+36);
  bf16x8 A0 = cvt8(a0,a1), A1 = cvt8(a2,a3);
  const float* biases[4] = {b_sg,b_dg,b_su,b_du};
  float* outs[4] = {e_src,e_dst,A_src,Bh};
  const int mats[4] = {0,1,3,4};
  #pragma unroll
  for (int i=0;i<4;i++){
    #pragma unroll
    for (int nt=0;nt<4;nt++){
      f32x4 acc = {0.f,0.f,0.f,0.f};
      acc = MFMA(A0, Wp[(mats[i]*8+nt)*64+lane],   acc);
      acc = MFMA(A1, Wp[(mats[i]*8+4+nt)*64+lane], acc);
      int col = c + nt*16;
      float bb = biases[i][col];
      #pragma unroll
      for (int e=0;e<4;e++){
        long row = base + 4*g + e;
        outs[i][row*64 + col] = acc[e] + bb;
      }
    }
  }
}

// Pass 1 over edges: m = edge@W_eg + e_src[src] + e_dst[dst] + b;
// sigma = sigmoid(m); scatter-add sigma and Bh[src]*sigma to dst;
// accumulate edge BN stats (sum, sumsq) hierarchically.
__global__ __launch_bounds__(256) void edge_pass1(
    const float* __restrict__ ef, const int* __restrict__ src, const int* __restrict__ dst,
    const float* __restrict__ e_src, const float* __restrict__ e_dst,
    const float* __restrict__ Bh, const float* __restrict__ be,
    const bf16x8* __restrict__ Wp,
    float* __restrict__ ssh, float* __restrict__ ss,
    float* __restrict__ est, int ntiles)
{
  int lane = threadIdx.x & 63;
  int gw = blockIdx.x*4 + (threadIdx.x>>6);
  int nw = gridDim.x*4;
  int g = lane>>4, c = lane&15;
  bf16x8 B0[4], B1[4];
  #pragma unroll
  for (int nt=0;nt<4;nt++){ B0[nt]=Wp[(16+nt)*64+lane]; B1[nt]=Wp[(20+nt)*64+lane]; }
  float bias[4];
  #pragma unroll
  for (int nt=0;nt<4;nt++) bias[nt] = be[c+nt*16];
  float s1[4]={0,0,0,0}, s2[4]={0,0,0,0};
  for (int t=gw; t<ntiles; t+=nw){
    long base = (long)t*16;
    const float* rp = ef + (base+c)*64 + g*8;
    float4 a0=*(const float4*)rp,      a1=*(const float4*)(rp+4);
    float4 a2=*(const float4*)(rp+32), a3=*(const float4*)(rp+36);
    bf16x8 A0=cvt8(a0,a1), A1=cvt8(a2,a3);
    f32x4 acc[4];
    #pragma unroll
    for (int nt=0;nt<4;nt++){
      acc[nt]=f32x4{0.f,0.f,0.f,0.f};
      acc[nt]=MFMA(A0,B0[nt],acc[nt]);
      acc[nt]=MFMA(A1,B1[nt],acc[nt]);
    }
    int4 sv = *(const int4*)(src+base+4*g);
    int4 dv = *(const int4*)(dst+base+4*g);
    int se[4]={sv.x,sv.y,sv.z,sv.w};
    int de[4]={dv.x,dv.y,dv.z,dv.w};
    #pragma unroll
    for (int e=0;e<4;e++){
      long so=(long)se[e]*64, dd=(long)de[e]*64;
      #pragma unroll
      for (int nt=0;nt<4;nt++){
        int col=c+nt*16;
        float mv = acc[nt][e] + e_src[so+col] + e_dst[dd+col] + bias[nt];
        float sg = 1.f/(1.f+__expf(-mv));
        atomicAdd(&ss[dd+col], sg);
        atomicAdd(&ssh[dd+col], Bh[so+col]*sg);
        s1[nt]+=mv; s2[nt]+=mv*mv;
      }
    }
  }
  #pragma unroll
  for (int nt=0;nt<4;nt++){
    float a=s1[nt], b=s2[nt];
    a+=__shfl_xor(a,16,64); a+=__shfl_xor(a,32,64);
    b+=__shfl_xor(b,16,64); b+=__shfl_xor(b,32,64);
    if (lane<16){ atomicAdd(&est[c+nt*16],a); atomicAdd(&est[64+c+nt*16],b); }
  }
}

// Node BN stats over x_pre = A_src + ssh/(ss+1e-6)
__global__ __launch_bounds__(256) void node_stats(
    const float* __restrict__ A_src, const float* __restrict__ ssh,
    const float* __restrict__ ss, float* __restrict__ nst, int Nn)
{
  int tid = blockIdx.x*blockDim.x + threadIdx.x;
  int col = tid & 63;
  int row0 = tid >> 6;
  int rstride = (gridDim.x*blockDim.x) >> 6;
  float s=0.f, q=0.f;
  for (int r=row0; r<Nn; r+=rstride){
    long i = (long)r*64 + col;
    float x = A_src[i] + ssh[i]/(ss[i]+1e-6f);
    s += x; q += x*x;
  }
  atomicAdd(&nst[col], s); atomicAdd(&nst[64+col], q);
}

// Final x = node_feats + silu(bn(x_pre))
__global__ __launch_bounds__(256) void node_final(
    const float* __restrict__ nf, const float* __restrict__ A_src,
    const float* __restrict__ ssh, const float* __restrict__ ss,
    const float* __restrict__ nst, const float* __restrict__ gam,
    const float* __restrict__ bet, float* __restrict__ xo, int Nn)
{
  long tid = blockIdx.x*blockDim.x + threadIdx.x;
  long stride = (long)gridDim.x*blockDim.x;    // multiple of 64
  int col = (int)(tid & 63);
  float invN = 1.f/(float)Nn;
  float mu = nst[col]*invN;
  float var = nst[64+col]*invN - mu*mu;
  float rs = rsqrtf(var + 1e-5f);
  float aa = gam[col]*rs;
  float bb = bet[col] - mu*aa;
  long total = (long)Nn*64;
  for (long i=tid; i<total; i+=stride){
    float xp = A_src[i] + ssh[i]/(ss[i]+1e-6f);
    float z = xp*aa + bb;
    xo[i] = nf[i] + z/(1.f+__expf(-z));
  }
}

// Pass 2 over edges: recompute m (identical arithmetic), y = ef + silu(bn(m))
__global__ __launch_bounds__(256) void edge_pass2(
    const float* __restrict__ ef, const int* __restrict__ src, const int* __restrict__ dst,
    const float* __restrict__ e_src, const float* __restrict__ e_dst,
    const float* __restrict__ be, const bf16x8* __restrict__ Wp,
    const float* __restrict__ est, const float* __restrict__ gam,
    const float* __restrict__ bet, float* __restrict__ y, float invE, int ntiles)
{
  int lane = threadIdx.x & 63;
  int gw = blockIdx.x*4 + (threadIdx.x>>6);
  int nw = gridDim.x*4;
  int g = lane>>4, c = lane&15;
  bf16x8 B0[4], B1[4];
  #pragma unroll
  for (int nt=0;nt<4;nt++){ B0[nt]=Wp[(16+nt)*64+lane]; B1[nt]=Wp[(20+nt)*64+lane]; }
  float bias[4], aa[4], bb2[4];
  #pragma unroll
  for (int nt=0;nt<4;nt++){
    int col = c + nt*16;
    bias[nt] = be[col];
    float mu = est[col]*invE;
    float var = est[64+col]*invE - mu*mu;
    float rs = rsqrtf(var + 1e-5f);
    float ga = gam[col]*rs;
    aa[nt] = ga; bb2[nt] = bet[col] - mu*ga;
  }
  for (int t=gw; t<ntiles; t+=nw){
    long base = (long)t*16;
    const float* rp = ef + (base+c)*64 + g*8;
    float4 a0=*(const float4*)rp,      a1=*(const float4*)(rp+4);
    float4 a2=*(const float4*)(rp+32), a3=*(const float4*)(rp+36);
    bf16x8 A0=cvt8(a0,a1), A1=cvt8(a2,a3);
    f32x4 acc[4];
    #pragma unroll
    for (int nt=0;nt<4;nt++){
      acc[nt]=f32x4{0.f,0.f,0.f,0.f};
      acc[nt]=MFMA(A0,B0[nt],acc[nt]);
      acc[nt]=MFMA(A1,B1[nt],acc[nt]);
    }
    int4 sv = *(const int4*)(src+base+4*g);
    int4 dv = *(const int4*)(dst+base+4*g);
    int se[4]={sv.x,sv.y,sv.z,sv.w};
    int de[4]={dv.x,dv.y,dv.z,dv.w};
    #pragma unroll
    for (int e=0;e<4;e++){
      long so=(long)se[e]*64, dd=(long)de[e]*64;
      long er = base + 4*g + e;
      #pragma unroll
      for (int nt=0;nt<4;nt++){
        int col=c+nt*16;
        float mv = acc[nt][e] + e_src[so+col] + e_dst[dd+col] + bias[nt];
        float z = mv*aa[nt] + bb2[nt];
        float sil = z/(1.f+__expf(-z));
        y[er*64+col] = ef[er*64+col] + sil;
      }
    }
  }
}

extern "C" void kernel_launch(void* const* d_in, const int* in_sizes, int n_in,
                              void* d_out, int out_size, void* d_ws, size_t ws_size,
                              hipStream_t stream){
  const float* nf  = (const float*)d_in[0];
  const float* ef  = (const float*)d_in[1];
  const int*   src = (const int*)d_in[2];
  const int*   dst = (const int*)d_in[3];
  const float* W_sg=(const float*)d_in[4];  const float* b_sg=(const float*)d_in[5];
  const float* W_dg=(const float*)d_in[6];  const float* b_dg=(const float*)d_in[7];
  const float* W_eg=(const float*)d_in[8];  const float* b_eg=(const float*)d_in[9];
  const float* W_su=(const float*)d_in[10]; const float* b_su=(const float*)d_in[11];
  const float* W_du=(const float*)d_in[12]; const float* b_du=(const float*)d_in[13];
  const float* gn=(const float*)d_in[14];   const float* btn=(const float*)d_in[15];
  const float* ge=(const float*)d_in[16];   const float* bte=(const float*)d_in[17];

  int Nn = in_sizes[0]/64;
  int Ee = in_sizes[2];
  size_t Nf = (size_t)Nn*64;

  float* ws    = (float*)d_ws;
  float* e_src = ws;
  float* e_dst = ws + Nf;
  float* Bh    = ws + 2*Nf;
  float* A_src = ws + 3*Nf;
  float* ssh   = ws + 4*Nf;
  float* ss    = ws + 5*Nf;
  float* est   = ws + 6*Nf;         // 128 floats (sum, sumsq) edges
  float* nst   = ws + 6*Nf + 128;   // 128 floats nodes
  bf16x8* Wp   = (bf16x8*)(ws + 6*Nf + 256);

  float* xo = (float*)d_out;
  float* yo = xo + Nf;

  // zero scatter buffers + stats (must re-init every call)
  hipMemsetAsync(ssh, 0, (2*Nf + 256)*sizeof(float), stream);

  wcvt<<<10,256,0,stream>>>(W_sg,W_dg,W_eg,W_su,W_du,Wp);

  int ntn = Nn/16;
  node_xform<<<(ntn+3)/4,256,0,stream>>>(nf,Wp,b_sg,b_dg,b_su,b_du,
                                         e_src,e_dst,A_src,Bh,ntn);
  int nte = Ee/16;
  edge_pass1<<<1024,256,0,stream>>>(ef,src,dst,e_src,e_dst,Bh,b_eg,Wp,ssh,ss,est,nte);
  node_stats<<<512,256,0,stream>>>(A_src,ssh,ss,nst,Nn);
  node_final<<<1024,256,0,stream>>>(nf,A_src,ssh,ss,nst,gn,btn,xo,Nn);
  edge_pass2<<<1024,256,0,stream>>>(ef,src,dst,e_src,e_dst,b_eg,Wp,est,ge,bte,yo,
                                    1.f/(float)Ee,nte);
}